// Round 7
// baseline (202.018 us; speedup 1.0000x reference)
//
#include <hip/hip_runtime.h>
#include <hip/hip_bf16.h>

// Model: one_hot -> 3x Conv2D(5,(4,4),(1,2),SAME) -> [B,S=1024,D=20]
//        -> 3x causal self-attention -> flatten -> 3x Dense(10)
// B=64, L=8192, S=1024, D=20.
// R23 (198.5us): attn 512-thr, (q-subtile,t-half) waves, zero-barrier loop.
// R25 (199.2us): fragment-major V (Vf), no LDS staging in attn. Neutral ->
//      attn at its structural floor; calibration (R22: mega 852 vs total 965)
//      says ~113us of dur_us is harness fill/graph overhead -> controllable
//      budget ~86us over 6 kernels.
// R26: conv kernels get the occupancy/coalescing treatment (never touched):
//      - conv12: thread=(wo,pos): conv2's kw-reduction split over 4 threads,
//        quad shfl_xor butterfly combine. 524288 thr = 8 waves/SIMD (was 2),
//        per-thread FMA 1600->400, input gathers quad-contiguous.
//      - conv3_proj: thread=(row,part): conv3 kw-split + butterfly; proj cols
//        5p..5p+4 per thread (FUSE-epilogue write pattern). 262144 thr =
//        4 waves/SIMD (was 1!), c2 gathers 80B-contiguous per quad.
//      attn/dense/workspace = R25 verbatim. fp32 reassoc in butterfly -> tiny
//      absmax drift expected.

#define B_ 64
#define L_ 8192
#define S_ 1024
#define D_ 20

typedef unsigned short ushort_t;
typedef __attribute__((ext_vector_type(8))) short short8_t;  // 8 bf16 (4 VGPRs)
typedef __attribute__((ext_vector_type(4))) short short4_t;  // 4 bf16 (2 VGPRs)
typedef __attribute__((ext_vector_type(4))) float f32x4_t;   // MFMA C/D

__device__ __forceinline__ ushort_t f2bf(float f) {          // RNE fp32->bf16
  unsigned u = __float_as_uint(f);
  return (ushort_t)((u + 0x7fffu + ((u >> 16) & 1u)) >> 16);
}
__device__ __forceinline__ float bf2f(ushort_t h) {
  return __uint_as_float(((unsigned)h) << 16);
}

// ---------------- fused conv1+conv2 (+ W1 transpose tail) ----------------
// thread = (idx, pos): pos = conv2 kernel column. Each thread builds conv1
// output for ONE width w1=2wo-1+pos (20 vals) and the conv2 partial for
// kw=pos (400 FMA); quad butterfly sums the 4 partials; thread writes h=pos.
__global__ __launch_bounds__(256) void conv12_kernel(
    const int* __restrict__ inp,
    const float* __restrict__ W1c, const float* __restrict__ B1c,
    const float* __restrict__ W2c, const float* __restrict__ B2c,
    float* __restrict__ out,                      // c2 [B,4,2048,5]
    const float* __restrict__ W1d,                // dense W1 [20480,10]
    float* __restrict__ W1T) {                    // [10,20480]
  __shared__ float w1s[80], b1s[5], w2s[400], b2s[5];
  for (int j = threadIdx.x; j < 400; j += 256) w2s[j] = W2c[j];
  if (threadIdx.x < 80)      w1s[threadIdx.x]      = W1c[threadIdx.x];
  else if (threadIdx.x < 85) b1s[threadIdx.x - 80] = B1c[threadIdx.x - 80];
  else if (threadIdx.x < 90) b2s[threadIdx.x - 85] = B2c[threadIdx.x - 85];
  __syncthreads();
  const int j   = blockIdx.x * 256 + threadIdx.x;  // 524288 total
  const int pos = j & 3;
  const int idx = j >> 2;                          // 0..131071
  const int b   = idx >> 11;
  const int wo  = idx & 2047;
  const int* ib = inp + (size_t)b * L_;
  // ---- conv1 output column w1 = 2wo-1+pos (zero if out of conv2 SAME pad) -
  float vp[4][5];                                  // [hi][ci]
  const int w1 = 2 * wo - 1 + pos;
  const bool okp = (w1 >= 0 && w1 < 4096);
#pragma unroll
  for (int hi = 0; hi < 4; ++hi)
#pragma unroll
    for (int ci = 0; ci < 5; ++ci) vp[hi][ci] = okp ? b1s[ci] : 0.f;
  if (okp) {
#pragma unroll
    for (int kw = 0; kw < 4; ++kw) {
      const int gw = 2 * w1 - 1 + kw;
      if (gw >= 0 && gw < L_) {
        const int v = ib[gw];
#pragma unroll
        for (int hi = 0; hi < 4; ++hi) {
          const int kh = v - hi + 1;
          if (kh >= 0 && kh < 4) {
#pragma unroll
            for (int ci = 0; ci < 5; ++ci)
              vp[hi][ci] += w1s[(kh * 4 + kw) * 5 + ci];
          }
        }
      }
    }
  }
  // ---- conv2 partial for kw = pos ----
  float part[4][5];
#pragma unroll
  for (int h = 0; h < 4; ++h)
#pragma unroll
    for (int c = 0; c < 5; ++c) part[h][c] = 0.f;
#pragma unroll
  for (int kh = 0; kh < 4; ++kh)
#pragma unroll
    for (int ci = 0; ci < 5; ++ci) {
      const float* wp = w2s + ((kh * 4 + pos) * 5 + ci) * 5;
      float w0 = wp[0], w1v = wp[1], w2v = wp[2], w3v = wp[3], w4v = wp[4];
#pragma unroll
      for (int h = 0; h < 4; ++h) {
        int hi = h - 1 + kh;
        if (hi >= 0 && hi < 4) {
          float x = vp[hi][ci];
          part[h][0] += w0 * x;  part[h][1] += w1v * x; part[h][2] += w2v * x;
          part[h][3] += w3v * x; part[h][4] += w4v * x;
        }
      }
    }
  // ---- quad butterfly: sum partials over the 4 pos lanes ----
#pragma unroll
  for (int m = 1; m <= 2; m <<= 1)
#pragma unroll
    for (int h = 0; h < 4; ++h)
#pragma unroll
      for (int c = 0; c < 5; ++c) part[h][c] += __shfl_xor(part[h][c], m, 64);
  // ---- this thread writes h = pos (coalesced 20B-stride across wo) ----
  float* ob = out + (size_t)b * 4 * 2048 * 5;
#pragma unroll
  for (int c = 0; c < 5; ++c)
    ob[(pos * 2048 + wo) * 5 + c] = part[pos][c] + b2s[c];
  // ---- tail: W1 transpose ----
  for (int t = j; t < 204800; t += 524288) {
    int col = t / 20480, i2 = t - col * 20480;
    W1T[t] = W1d[i2 * 10 + col];
  }
}

// ---------------- fused conv3 + proj (layer 1) ----------------
// thread = (row, part): conv3's kwp-reduction split over 4 threads (quad
// butterfly), then thread computes proj cols 5*part..5*part+4 for q,k,v.
__global__ __launch_bounds__(256) void conv3_proj_kernel(
    const float* __restrict__ in,                 // c2 [B,4,2048,5]
    const float* __restrict__ W,  const float* __restrict__ Bi,
    const float* __restrict__ Kw, const float* __restrict__ Qw,
    const float* __restrict__ Vw,
    ushort_t* __restrict__ Qb, ushort_t* __restrict__ Kb,
    ushort_t* __restrict__ Vf) {                  // Vf[b][64][20][16]
  constexpr int WIN = 2048;
  __shared__ float ws[400], bs[5];
  __shared__ float kws[400], qws[400], vws[400];
  for (int i = threadIdx.x; i < 400; i += 256) {
    ws[i] = W[i]; kws[i] = Kw[i]; qws[i] = Qw[i]; vws[i] = Vw[i];
  }
  if (threadIdx.x < 5) bs[threadIdx.x] = Bi[threadIdx.x];
  __syncthreads();
  const int j  = blockIdx.x * 256 + threadIdx.x;  // 262144 total
  const int p  = j & 3;                           // part / conv3 kwp
  const int r  = j >> 2;                          // row 0..65535
  const int b  = r >> 10;
  const int wo = r & 1023;
  // ---- conv3 partial for kwp = p ----
  const int wi = 2 * wo - 1 + p;
  const bool ok = (wi >= 0 && wi < WIN);
  float vp[4][5];
#pragma unroll
  for (int hi = 0; hi < 4; ++hi) {
    const float* ir = in + ((size_t)b * 4 + hi) * WIN * 5;
#pragma unroll
    for (int ci = 0; ci < 5; ++ci) vp[hi][ci] = ok ? ir[wi * 5 + ci] : 0.f;
  }
  float part[4][5];
#pragma unroll
  for (int h = 0; h < 4; ++h)
#pragma unroll
    for (int c = 0; c < 5; ++c) part[h][c] = 0.f;
#pragma unroll
  for (int kh = 0; kh < 4; ++kh)
#pragma unroll
    for (int ci = 0; ci < 5; ++ci) {
      const float* wp = ws + ((kh * 4 + p) * 5 + ci) * 5;
      float w0 = wp[0], w1 = wp[1], w2 = wp[2], w3 = wp[3], w4 = wp[4];
#pragma unroll
      for (int h = 0; h < 4; ++h) {
        int hi = h - 1 + kh;
        if (hi >= 0 && hi < 4) {
          float x = vp[hi][ci];
          part[h][0] += w0 * x; part[h][1] += w1 * x; part[h][2] += w2 * x;
          part[h][3] += w3 * x; part[h][4] += w4 * x;
        }
      }
    }
#pragma unroll
  for (int m = 1; m <= 2; m <<= 1)
#pragma unroll
    for (int h = 0; h < 4; ++h)
#pragma unroll
      for (int c = 0; c < 5; ++c) part[h][c] += __shfl_xor(part[h][c], m, 64);
  float x[D_];
#pragma unroll
  for (int h = 0; h < 4; ++h)
#pragma unroll
    for (int c = 0; c < 5; ++c) x[h * 5 + c] = part[h][c] + bs[c];
  // ---- proj: this thread computes cols 5p..5p+4 of q,k,v ----
  float qv[5], kv[5], vv[5];
#pragma unroll
  for (int jj = 0; jj < 5; ++jj) { qv[jj] = 0.f; kv[jj] = 0.f; vv[jj] = 0.f; }
#pragma unroll
  for (int i = 0; i < D_; ++i) {
    const float xi = x[i];
#pragma unroll
    for (int jj = 0; jj < 5; ++jj) {
      const int col = 5 * p + jj;
      kv[jj] += xi * kws[i * D_ + col];
      qv[jj] += xi * qws[i * D_ + col];
      vv[jj] += xi * vws[i * D_ + col];
    }
  }
  const float sc = 0.22360679774997896f;  // 1/sqrt(20)
#pragma unroll
  for (int jj = 0; jj < 5; ++jj) {
    const int col = 5 * p + jj;
    Kb[(size_t)r * 32 + col] = f2bf(kv[jj]);
    Qb[(size_t)r * 32 + col] = f2bf(qv[jj] * sc);
    Vf[(size_t)b * 20480 + (size_t)(wo >> 4) * 320 + col * 16 + (wo & 15)] =
        f2bf(vv[jj]);
  }
  if (p == 0) {
#pragma unroll
    for (int u = 0; u < 6; ++u)
      *(unsigned*)(Kb + (size_t)r * 32 + 20 + 2 * u) = 0u;
  } else if (p == 1) {
#pragma unroll
    for (int u = 0; u < 6; ++u)
      *(unsigned*)(Qb + (size_t)r * 32 + 20 + 2 * u) = 0u;
  }
}

// ---------------- causal attention: 8 waves = (q-subtile, t-half) ---------
// S^T = mfma_16x16x32(Kfrag, Qfrag): lane (quad,n): S^T[t=quad*4+r][q=n].
// P^T register layout IS the B-operand of mfma_16x16x16; PV from registers.
// K and Vf both read DIRECT from global, fully coalesced (K: 1KB/wave instr;
// Vf vlo: one 512B segment; vhi: one 128B segment), L2-hot per b.
// No LDS staging at all; FUSE path has ONE barrier total.
// FUSE=true : epilogue projects O rows -> next layer's Qb2/Kb2/Vf2.
// FUSE=false: epilogue computes dense1 partial -> part2[b][strip][10].
template <bool FUSE>
__global__ __launch_bounds__(512, 8) void attn_kernel(
    const ushort_t* __restrict__ Qb, const ushort_t* __restrict__ Kb,
    const ushort_t* __restrict__ Vf,
    const float* __restrict__ Kw2, const float* __restrict__ Qw2,
    const float* __restrict__ Vw2,
    ushort_t* __restrict__ Qb2, ushort_t* __restrict__ Kb2,
    ushort_t* __restrict__ Vf2,
    const float* __restrict__ W1T,   // !FUSE: [10,20480]
    float* __restrict__ part2) {     // !FUSE: [64,16,10]
  __shared__ float ox[1280];                  // merged O rows [4 subtiles x 320]
  __shared__ float pw_s[FUSE ? 1200 : 4];     // proj weights (FUSE)
  __shared__ float mrgL[64];                  // half1 l partials [sub][n]
  __shared__ float red2[40];                  // !FUSE per-wave dense sums
  const int blk   = blockIdx.x;
  const int b     = blk & 63;                 // blk%8==b%8 -> XCD locality
  const int raw   = blk >> 6;                 // 0..15
  const int rr4   = raw & 3, k4 = raw >> 2;
  const int strip = (k4 == 0) ? rr4 : (k4 == 1) ? 7 - rr4
                  : (k4 == 2) ? 8 + rr4 : 15 - rr4;  // per-CU sum const
  const int q0    = strip * 64;
  const int nt    = q0 + 64;
  const int tid   = threadIdx.x;
  const int w     = tid >> 6;                 // wave 0..7
  const int sub   = w & 3;                    // q-subtile
  const int half  = w >> 2;                   // t-half
  const int lane  = tid & 63;
  const int n     = lane & 15;
  const int quad  = lane >> 4;
  const int qbase = q0 + 16 * sub;
  const int qg    = qbase + n;                // this lane's q column
  if (FUSE) {
    for (int i = tid; i < 1200; i += 512) {
      int m = i / 400, oo = i - m * 400;
      pw_s[i] = (m == 0) ? Kw2[oo] : (m == 1) ? Qw2[oo] : Vw2[oo];
    }
  }
  const ushort_t* KbB  = Kb + (size_t)b * 1024 * 32;
  const ushort_t* VfB  = Vf + (size_t)b * 20480;       // [64][20][16]
  const ushort_t* vloB = VfB + n * 16 + quad * 4;
  const ushort_t* vhiB = VfB + (16 + (n & 3)) * 16 + quad * 4;
  short8_t qfrag = *(const short8_t*)(Qb + ((size_t)(b * 1024 + qbase + n)) * 32 + quad * 8);
  f32x4_t oA = {0.f, 0.f, 0.f, 0.f};          // O^T[d=quad*4+r][q=n]
  f32x4_t oB = {0.f, 0.f, 0.f, 0.f};          // O^T[d=16+quad*4+r][q=n] (quad0)
  const f32x4_t zero = {0.f, 0.f, 0.f, 0.f};
  float lsum = 0.f;
  const int nt2 = nt >> 1;
  const int tlo = half ? nt2 : 0;
  int thi = half ? nt : nt2;
  if (thi > qbase + 16) thi = qbase + 16;     // wave-uniform: skip all-masked
  for (int t0 = tlo; t0 < thi; t0 += 32) {
    short8_t kf0 = *(const short8_t*)(KbB + (size_t)(t0 + n) * 32 + quad * 8);
    short8_t kf1 = *(const short8_t*)(KbB + (size_t)(t0 + 16 + n) * 32 + quad * 8);
#pragma unroll
    for (int c = 0; c < 2; ++c) {
      const int tg = t0 + c * 16 + quad * 4;  // global t of r=0
      f32x4_t s = __builtin_amdgcn_mfma_f32_16x16x32_bf16(c ? kf1 : kf0, qfrag,
                                                          zero, 0, 0, 0);
      ushort_t pk4[4];
#pragma unroll
      for (int r = 0; r < 4; ++r) {
        float p = (tg + r <= qg) ? __expf(s[r]) : 0.f;
        ushort_t h = f2bf(p);
        lsum += bf2f(h);                      // consistent with bf16 P in PV
        pk4[r] = h;
      }
      short4_t pfrag = *(const short4_t*)pk4; // B16-frag: k=quad*4+j, n=q
      const int tb = (t0 >> 4) + c;           // 16-t fragment block index
      short4_t vlo = *(const short4_t*)(vloB + tb * 320);
      short4_t vhi = *(const short4_t*)(vhiB + tb * 320);
      oA = __builtin_amdgcn_mfma_f32_16x16x16bf16_1k(vlo, pfrag, oA, 0, 0, 0);
      oB = __builtin_amdgcn_mfma_f32_16x16x16bf16_1k(vhi, pfrag, oB, 0, 0, 0);
    }
  }
  // l[q=n]: reduce partial sums across the 4 quads
  float l = lsum;
  l += __shfl_xor(l, 16, 64);
  l += __shfl_xor(l, 32, 64);
  float* oxw = ox + sub * 320;
  // ---- merge halves: half1 writes partials (ox layout), half0 adds ----
  if (half) {
#pragma unroll
    for (int r = 0; r < 4; ++r) oxw[n * 20 + quad * 4 + r] = oA[r];
    if (quad == 0) {
#pragma unroll
      for (int r = 0; r < 4; ++r) oxw[n * 20 + 16 + r] = oB[r];
      mrgL[sub * 16 + n] = l;
    }
  }
  __syncthreads();
  if (!half) {
#pragma unroll
    for (int r = 0; r < 4; ++r) oA[r] += oxw[n * 20 + quad * 4 + r];
    if (quad == 0) {
#pragma unroll
      for (int r = 0; r < 4; ++r) oB[r] += oxw[n * 20 + 16 + r];
    }
    l += mrgL[sub * 16 + n];                  // broadcast read per n
    const float inv = 1.f / l;
    // overwrite own region with normalized O
#pragma unroll
    for (int r = 0; r < 4; ++r) oxw[n * 20 + quad * 4 + r] = oA[r] * inv;
    if (quad == 0) {
#pragma unroll
      for (int r = 0; r < 4; ++r) oxw[n * 20 + 16 + r] = oB[r] * inv;
    }
  }
  if (FUSE) {
    if (!half) {
      __asm__ volatile("s_waitcnt lgkmcnt(0)" ::: "memory");  // wave LDS RAW
      const int row  = lane >> 2;     // 0..15
      const int part = lane & 3;      // cols 5*part .. 5*part+4
      float x[D_];
#pragma unroll
      for (int i = 0; i < D_; ++i) x[i] = oxw[row * 20 + i];
      float qv[5], kv[5], vv[5];
#pragma unroll
      for (int jj = 0; jj < 5; ++jj) { qv[jj] = 0.f; kv[jj] = 0.f; vv[jj] = 0.f; }
#pragma unroll
      for (int i = 0; i < D_; ++i) {
        const float xi = x[i];
#pragma unroll
        for (int jj = 0; jj < 5; ++jj) {
          const int j = 5 * part + jj;
          kv[jj] += xi * pw_s[i * 20 + j];          // K block
          qv[jj] += xi * pw_s[400 + i * 20 + j];    // Q block
          vv[jj] += xi * pw_s[800 + i * 20 + j];    // V block
        }
      }
      const float sc = 0.22360679774997896f;
      const int rg = b * 1024 + qbase + row;
      const int s  = rg & 1023;
#pragma unroll
      for (int jj = 0; jj < 5; ++jj) {
        const int j = 5 * part + jj;
        Kb2[(size_t)rg * 32 + j] = f2bf(kv[jj]);
        Qb2[(size_t)rg * 32 + j] = f2bf(qv[jj] * sc);
        Vf2[(size_t)b * 20480 + (size_t)(s >> 4) * 320 + j * 16 + (s & 15)] =
            f2bf(vv[jj]);
      }
      if (part == 0) {
#pragma unroll
        for (int u = 0; u < 6; ++u)
          *(unsigned*)(Kb2 + (size_t)rg * 32 + 20 + 2 * u) = 0u;
      } else if (part == 1) {
#pragma unroll
        for (int u = 0; u < 6; ++u)
          *(unsigned*)(Qb2 + (size_t)rg * 32 + 20 + 2 * u) = 0u;
      }
    }
  } else {
    // ---- fused dense1 partial over this block's 64 rows ----
    __syncthreads();                     // normalized ox visible to all
    float acc[10];
#pragma unroll
    for (int j = 0; j < 10; ++j) acc[j] = 0.f;
    const int base = q0 * 20;
    if (tid < 256) {
#pragma unroll
      for (int k = 0; k < 5; ++k) {
        const int il = tid + 256 * k;
        const float xv = ox[il];
#pragma unroll
        for (int j = 0; j < 10; ++j)
          acc[j] += xv * W1T[(size_t)j * 20480 + base + il];  // lane-coalesced
      }
    }
    // wave butterfly reduce (tid>=256 contribute zeros)
#pragma unroll
    for (int off = 1; off < 64; off <<= 1) {
#pragma unroll
      for (int j = 0; j < 10; ++j) acc[j] += __shfl_xor(acc[j], off, 64);
    }
    if (tid < 256 && lane == 0) {
#pragma unroll
      for (int j = 0; j < 10; ++j) red2[w * 10 + j] = acc[j];
    }
    __syncthreads();
    if (tid < 10) {
      float s2 = red2[tid] + red2[10 + tid] + red2[20 + tid] + red2[30 + tid];
      part2[((b << 4) + strip) * 10 + tid] = s2;
    }
  }
}

// ---------------- dense head: combine strips + dense2/3 ----------------
__global__ __launch_bounds__(64) void dense_final(
    const float* __restrict__ part2,   // [64,16,10], strip-ordered
    const float* __restrict__ B1,
    const float* __restrict__ W2, const float* __restrict__ B2,
    const float* __restrict__ W3, const float* __restrict__ B3,
    float* __restrict__ out) {
  const int b = blockIdx.x;
  __shared__ float y1[10], y2[10];
  if (threadIdx.x < 10) {
    int j = threadIdx.x;
    float s = 0.f;
#pragma unroll
    for (int st = 0; st < 16; ++st) s += part2[((b << 4) + st) * 10 + j];
    y1[j] = s + B1[j];
  }
  __syncthreads();
  if (threadIdx.x < 10) {
    int j = threadIdx.x;
    float s = B2[j];
#pragma unroll
    for (int i = 0; i < 10; ++i) s += y1[i] * W2[i * 10 + j];
    y2[j] = s;
  }
  __syncthreads();
  if (threadIdx.x < 10) {
    int j = threadIdx.x;
    float s = B3[j];
#pragma unroll
    for (int i = 0; i < 10; ++i) s += y2[i] * W3[i * 10 + j];
    out[b * 10 + j] = s;
  }
}

extern "C" void kernel_launch(void* const* d_in, const int* in_sizes, int n_in,
                              void* d_out, int out_size, void* d_ws, size_t ws_size,
                              hipStream_t stream) {
  const int*   inp = (const int*)d_in[0];
  const float* cw1 = (const float*)d_in[1];
  const float* cb1 = (const float*)d_in[2];
  const float* cw2 = (const float*)d_in[3];
  const float* cb2 = (const float*)d_in[4];
  const float* cw3 = (const float*)d_in[5];
  const float* cb3 = (const float*)d_in[6];
  const float* a1K = (const float*)d_in[7];
  const float* a1Q = (const float*)d_in[8];
  const float* a1V = (const float*)d_in[9];
  const float* a2K = (const float*)d_in[10];
  const float* a2Q = (const float*)d_in[11];
  const float* a2V = (const float*)d_in[12];
  const float* a3K = (const float*)d_in[13];
  const float* a3Q = (const float*)d_in[14];
  const float* a3V = (const float*)d_in[15];
  const float* dw1 = (const float*)d_in[16];
  const float* db1 = (const float*)d_in[17];
  const float* dw2 = (const float*)d_in[18];
  const float* db2 = (const float*)d_in[19];
  const float* dw3 = (const float*)d_in[20];
  const float* db3 = (const float*)d_in[21];
  float* outp = (float*)d_out;

  // workspace layout (float units) — R19 offsets; Vf fits old V^T regions
  float* wsf = (float*)d_ws;
  ushort_t* qbA  = (ushort_t*)(wsf);            // [65536][32] bf16  [0 .. 1,048,576)
  ushort_t* kbA  = (ushort_t*)(wsf + 1048576);  //                   [1,048,576 .. 2,097,152)
  ushort_t* vfA  = (ushort_t*)(wsf + 2097152);  // Vf[64][64][20][16] (655,360 f)
  float*    part2= wsf + 4456448;               // [64,16,10]
  float*    w1t  = wsf + 4466688;               // [10,20480]        ends 4,671,488
  ushort_t* qbB  = (ushort_t*)(wsf + 4671488);  // ends 5,195,776
  ushort_t* kbB  = (ushort_t*)(wsf + 5712384);  // B-buffers overlap dead c2 region
  ushort_t* vfB  = (ushort_t*)(wsf + 6760960);  //   (c2 consumed before attn1 writes B)
  float*    c2   = wsf + 5242880;               // [B,4,2048,5]      [5,242,880 .. 7,864,320)

  conv12_kernel<<<2048, 256, 0, stream>>>(inp, cw1, cb1, cw2, cb2, c2, dw1, w1t);

  conv3_proj_kernel<<<1024, 256, 0, stream>>>(c2, cw3, cb3, a1K, a1Q, a1V, qbA, kbA, vfA);
  // attn1: reads A, fused proj(layer2) -> B
  attn_kernel<true><<<1024, 512, 0, stream>>>(
      qbA, kbA, vfA, a2K, a2Q, a2V, qbB, kbB, vfB, nullptr, nullptr);
  // attn2: reads B, fused proj(layer3) -> A
  attn_kernel<true><<<1024, 512, 0, stream>>>(
      qbB, kbB, vfB, a3K, a3Q, a3V, qbA, kbA, vfA, nullptr, nullptr);
  // attn3: reads A, fused dense1 partial -> part2
  attn_kernel<false><<<1024, 512, 0, stream>>>(
      qbA, kbA, vfA, nullptr, nullptr, nullptr, nullptr, nullptr, nullptr,
      w1t, part2);

  dense_final<<<64, 64, 0, stream>>>(part2, db1, dw2, db2, dw3, db3, outp);
}